// Round 1
// baseline (799.842 us; speedup 1.0000x reference)
//
#include <hip/hip_runtime.h>
#include <math.h>

// Problem constants (GumbelVectorQuantizer): B=16,T=2048,D=512,M=1024
#define NTOT 32768   // B*T
#define DDIM 512
#define MDIM 1024
#define BN   32      // rows per block
#define KC   8       // k per LDS slab
#define NSLAB (DDIM / KC)
#define QOFF 16777216  // quantized element count (output scalars follow)

// ---------------------------------------------------------------------------
// async global->LDS (16B per lane, wave-uniform LDS base)
__device__ __forceinline__ void gload_lds16(const void* g, void* l) {
  __builtin_amdgcn_global_load_lds(
      (const __attribute__((address_space(1))) void*)g,
      (__attribute__((address_space(3))) void*)l, 16, 0, 0);
}

// ---------------------------------------------------------------------------
// Transpose embedding [M][D] -> Et [D][M] so K-slabs are contiguous 32KB.
__global__ __launch_bounds__(256) void transpose_e(const float* __restrict__ e,
                                                   float* __restrict__ et) {
  __shared__ float tile[64][65];
  const int t = threadIdx.x;
  const int kb = (blockIdx.x & 7) * 64;   // 8 k-blocks  (512)
  const int mb = (blockIdx.x >> 3) * 64;  // 16 m-blocks (1024)
#pragma unroll
  for (int i = 0; i < 16; ++i) {
    const int idx = i * 256 + t;
    const int rr = idx >> 6, cc = idx & 63;
    tile[rr][cc] = e[(size_t)(mb + rr) * DDIM + kb + cc];
  }
  __syncthreads();
#pragma unroll
  for (int i = 0; i < 16; ++i) {
    const int idx = i * 256 + t;
    const int rr = idx >> 6, cc = idx & 63;
    et[(size_t)(kb + rr) * MDIM + mb + cc] = tile[cc][rr];
  }
}

// ---------------------------------------------------------------------------
// esq[m] = sum_d e[m][d]^2   (tree-reduced: accuracy matters for argmax)
__global__ __launch_bounds__(256) void esq_kernel(const float* __restrict__ e,
                                                  float* __restrict__ esq) {
  const int w = threadIdx.x >> 6, lane = threadIdx.x & 63;
  const int m = blockIdx.x * 4 + w;
  const float4* row = (const float4*)(e + (size_t)m * DDIM);
  const float4 a = row[lane * 2];
  const float4 b = row[lane * 2 + 1];
  float s = ((a.x * a.x + a.y * a.y) + (a.z * a.z + a.w * a.w)) +
            ((b.x * b.x + b.y * b.y) + (b.z * b.z + b.w * b.w));
#pragma unroll
  for (int off = 32; off; off >>= 1) s += __shfl_xor(s, off);
  if (lane == 0) esq[m] = s;
}

// ---------------------------------------------------------------------------
// Main fused kernel: G = X.E^T, argmax, online softmax->avg_probs, gumbel
// argmax -> quantized gather + commitment SSE.
// 8 waves/block; wave owns 4 rows; per-thread 4x16 fp32 micro-tile.
#define KSTEP(KK, X0, X1, X2, X3)                                              \
  {                                                                            \
    _Pragma("unroll") for (int j2 = 0; j2 < 4; ++j2) {                         \
      const float4 ev = *(const float4*)&Es[cur][KK][co + 256 * j2];           \
      acc[0][j2].x += (X0) * ev.x; acc[0][j2].y += (X0) * ev.y;                \
      acc[0][j2].z += (X0) * ev.z; acc[0][j2].w += (X0) * ev.w;                \
      acc[1][j2].x += (X1) * ev.x; acc[1][j2].y += (X1) * ev.y;                \
      acc[1][j2].z += (X1) * ev.z; acc[1][j2].w += (X1) * ev.w;                \
      acc[2][j2].x += (X2) * ev.x; acc[2][j2].y += (X2) * ev.y;                \
      acc[2][j2].z += (X2) * ev.z; acc[2][j2].w += (X2) * ev.w;                \
      acc[3][j2].x += (X3) * ev.x; acc[3][j2].y += (X3) * ev.y;                \
      acc[3][j2].z += (X3) * ev.z; acc[3][j2].w += (X3) * ev.w;                \
    }                                                                          \
  }

#define AMAX(V, MM)                                                            \
  { const float v_ = (V); const int m_ = (MM);                                 \
    if (v_ > bv || (v_ == bv && m_ < bi)) { bv = v_; bi = m_; } }
#define GMAX(V, MM)                                                            \
  { const float v_ = (V); const int m_ = (MM);                                 \
    if (v_ > gv || (v_ == gv && m_ < gi)) { gv = v_; gi = m_; } }

__global__ __launch_bounds__(512)
void vq_main(const float* __restrict__ x, const float* __restrict__ emb,
             const float* __restrict__ et, const float* __restrict__ gum,
             const float* __restrict__ esq, float* __restrict__ out,
             float* __restrict__ avg_acc, int* __restrict__ counts,
             float* __restrict__ sse) {
  __shared__ float Es[2][KC][MDIM];  // 64 KB double-buffered E slab [k][m]
  __shared__ float esq_s[MDIM];      // 4 KB
  __shared__ float avg_s[MDIM];      // 4 KB

  const int t = threadIdx.x;
  const int w = t >> 6;
  const int lane = t & 63;
  const int co = lane << 2;  // column base within each 256-group
  const int n0 = blockIdx.x * BN;

  avg_s[t] = 0.f; avg_s[t + 512] = 0.f;
  esq_s[t] = esq[t]; esq_s[t + 512] = esq[t + 512];

  float4 acc[4][4];
#pragma unroll
  for (int i = 0; i < 4; ++i)
#pragma unroll
    for (int j = 0; j < 4; ++j) acc[i][j] = make_float4(0.f, 0.f, 0.f, 0.f);

  const int stg = w * 4096 + lane * 16;  // this lane's byte offset in 32KB slab
  // prologue: stage slab 0
#pragma unroll
  for (int c = 0; c < 4; ++c)
    gload_lds16((const char*)et + stg + c * 1024,
                (char*)(&Es[0][0][0]) + w * 4096 + c * 1024);

  const float* xp0 = x + (size_t)(n0 + 4 * w + 0) * DDIM;
  const float* xp1 = x + (size_t)(n0 + 4 * w + 1) * DDIM;
  const float* xp2 = x + (size_t)(n0 + 4 * w + 2) * DDIM;
  const float* xp3 = x + (size_t)(n0 + 4 * w + 3) * DDIM;

  for (int kc = 0; kc < NSLAB; ++kc) {
    const int cur = kc & 1;
    __syncthreads();  // slab kc resident after the implicit vmcnt(0) drain
    if (kc + 1 < NSLAB) {
      const char* base = (const char*)et + (size_t)(kc + 1) * (KC * MDIM * 4);
      char* ldst = (char*)(&Es[cur ^ 1][0][0]) + w * 4096;
#pragma unroll
      for (int c = 0; c < 4; ++c)
        gload_lds16(base + stg + c * 1024, ldst + c * 1024);
    }
    const int k0 = kc * KC;
    const float4 a0 = *(const float4*)(xp0 + k0);
    const float4 a1 = *(const float4*)(xp1 + k0);
    const float4 a2 = *(const float4*)(xp2 + k0);
    const float4 a3 = *(const float4*)(xp3 + k0);
    KSTEP(0, a0.x, a1.x, a2.x, a3.x)
    KSTEP(1, a0.y, a1.y, a2.y, a3.y)
    KSTEP(2, a0.z, a1.z, a2.z, a3.z)
    KSTEP(3, a0.w, a1.w, a2.w, a3.w)
    const float4 b0 = *(const float4*)(xp0 + k0 + 4);
    const float4 b1 = *(const float4*)(xp1 + k0 + 4);
    const float4 b2 = *(const float4*)(xp2 + k0 + 4);
    const float4 b3 = *(const float4*)(xp3 + k0 + 4);
    KSTEP(4, b0.x, b1.x, b2.x, b3.x)
    KSTEP(5, b0.y, b1.y, b2.y, b3.y)
    KSTEP(6, b0.z, b1.z, b2.z, b3.z)
    KSTEP(7, b0.w, b1.w, b2.w, b3.w)
  }

  // ----- epilogue: per-row reductions (rows live entirely within one wave)
  const float4 es0 = *(const float4*)&esq_s[co];
  const float4 es1 = *(const float4*)&esq_s[co + 256];
  const float4 es2 = *(const float4*)&esq_s[co + 512];
  const float4 es3 = *(const float4*)&esq_s[co + 768];
  float4 cav0 = make_float4(0.f, 0.f, 0.f, 0.f);
  float4 cav1 = make_float4(0.f, 0.f, 0.f, 0.f);
  float4 cav2 = make_float4(0.f, 0.f, 0.f, 0.f);
  float4 cav3 = make_float4(0.f, 0.f, 0.f, 0.f);

#pragma unroll
  for (int i = 0; i < 4; ++i) {
    const int n = n0 + 4 * w + i;
    // dmap' (row-shift-invariant part): 10*g - 5*||e||^2
    float4 d0, d1, d2, d3;
    d0.x = 10.f * acc[i][0].x - 5.f * es0.x; d0.y = 10.f * acc[i][0].y - 5.f * es0.y;
    d0.z = 10.f * acc[i][0].z - 5.f * es0.z; d0.w = 10.f * acc[i][0].w - 5.f * es0.w;
    d1.x = 10.f * acc[i][1].x - 5.f * es1.x; d1.y = 10.f * acc[i][1].y - 5.f * es1.y;
    d1.z = 10.f * acc[i][1].z - 5.f * es1.z; d1.w = 10.f * acc[i][1].w - 5.f * es1.w;
    d2.x = 10.f * acc[i][2].x - 5.f * es2.x; d2.y = 10.f * acc[i][2].y - 5.f * es2.y;
    d2.z = 10.f * acc[i][2].z - 5.f * es2.z; d2.w = 10.f * acc[i][2].w - 5.f * es2.w;
    d3.x = 10.f * acc[i][3].x - 5.f * es3.x; d3.y = 10.f * acc[i][3].y - 5.f * es3.y;
    d3.z = 10.f * acc[i][3].z - 5.f * es3.z; d3.w = 10.f * acc[i][3].w - 5.f * es3.w;

    // hard argmax (first-index tiebreak)
    float bv = -3.402823466e+38f; int bi = 0;
    AMAX(d0.x, co + 0)   AMAX(d0.y, co + 1)   AMAX(d0.z, co + 2)   AMAX(d0.w, co + 3)
    AMAX(d1.x, co + 256) AMAX(d1.y, co + 257) AMAX(d1.z, co + 258) AMAX(d1.w, co + 259)
    AMAX(d2.x, co + 512) AMAX(d2.y, co + 513) AMAX(d2.z, co + 514) AMAX(d2.w, co + 515)
    AMAX(d3.x, co + 768) AMAX(d3.y, co + 769) AMAX(d3.z, co + 770) AMAX(d3.w, co + 771)
#pragma unroll
    for (int off = 32; off; off >>= 1) {
      const float ov = __shfl_xor(bv, off);
      const int oi = __shfl_xor(bi, off);
      if (ov > bv || (ov == bv && oi < bi)) { bv = ov; bi = oi; }
    }
    if (lane == 0) atomicAdd(&counts[bi], 1);

    // softmax(dmap) -> avg_probs contribution (bv is the row max)
    float4 p0, p1, p2, p3;
    p0.x = __expf(d0.x - bv); p0.y = __expf(d0.y - bv); p0.z = __expf(d0.z - bv); p0.w = __expf(d0.w - bv);
    p1.x = __expf(d1.x - bv); p1.y = __expf(d1.y - bv); p1.z = __expf(d1.z - bv); p1.w = __expf(d1.w - bv);
    p2.x = __expf(d2.x - bv); p2.y = __expf(d2.y - bv); p2.z = __expf(d2.z - bv); p2.w = __expf(d2.w - bv);
    p3.x = __expf(d3.x - bv); p3.y = __expf(d3.y - bv); p3.z = __expf(d3.z - bv); p3.w = __expf(d3.w - bv);
    float ssum = (((p0.x + p0.y) + (p0.z + p0.w)) + ((p1.x + p1.y) + (p1.z + p1.w))) +
                 (((p2.x + p2.y) + (p2.z + p2.w)) + ((p3.x + p3.y) + (p3.z + p3.w)));
#pragma unroll
    for (int off = 32; off; off >>= 1) ssum += __shfl_xor(ssum, off);
    const float inv = 1.0f / ssum;
    cav0.x += p0.x * inv; cav0.y += p0.y * inv; cav0.z += p0.z * inv; cav0.w += p0.w * inv;
    cav1.x += p1.x * inv; cav1.y += p1.y * inv; cav1.z += p1.z * inv; cav1.w += p1.w * inv;
    cav2.x += p2.x * inv; cav2.y += p2.y * inv; cav2.z += p2.z * inv; cav2.w += p2.w * inv;
    cav3.x += p3.x * inv; cav3.y += p3.y * inv; cav3.z += p3.z * inv; cav3.w += p3.w * inv;

    // gumbel path argmax -> quantized index
    const float4* grow = (const float4*)(gum + (size_t)n * MDIM);
    float gv = -3.402823466e+38f; int gi = 0;
    {
      const float4 g0 = grow[lane];
      const float4 g1 = grow[lane + 64];
      const float4 g2 = grow[lane + 128];
      const float4 g3 = grow[lane + 192];
      GMAX(d0.x + g0.x, co + 0)   GMAX(d0.y + g0.y, co + 1)
      GMAX(d0.z + g0.z, co + 2)   GMAX(d0.w + g0.w, co + 3)
      GMAX(d1.x + g1.x, co + 256) GMAX(d1.y + g1.y, co + 257)
      GMAX(d1.z + g1.z, co + 258) GMAX(d1.w + g1.w, co + 259)
      GMAX(d2.x + g2.x, co + 512) GMAX(d2.y + g2.y, co + 513)
      GMAX(d2.z + g2.z, co + 514) GMAX(d2.w + g2.w, co + 515)
      GMAX(d3.x + g3.x, co + 768) GMAX(d3.y + g3.y, co + 769)
      GMAX(d3.z + g3.z, co + 770) GMAX(d3.w + g3.w, co + 771)
    }
#pragma unroll
    for (int off = 32; off; off >>= 1) {
      const float ov = __shfl_xor(gv, off);
      const int oi = __shfl_xor(gi, off);
      if (ov > gv || (ov == gv && oi < gi)) { gv = ov; gi = oi; }
    }

    // quantized[n] = embedding[gi]; commitment SSE
    const float4* erow = (const float4*)(emb + (size_t)gi * DDIM);
    const float4* xrow = (const float4*)(x + (size_t)n * DDIM);
    float4* orow = (float4*)(out + (size_t)n * DDIM);
    float ss = 0.f;
#pragma unroll
    for (int c2 = 0; c2 < 2; ++c2) {
      const int f = lane + 64 * c2;
      const float4 ev = erow[f];
      const float4 xv = xrow[f];
      orow[f] = ev;
      const float q0 = xv.x - ev.x, q1 = xv.y - ev.y;
      const float q2 = xv.z - ev.z, q3 = xv.w - ev.w;
      ss += (q0 * q0 + q1 * q1) + (q2 * q2 + q3 * q3);
    }
#pragma unroll
    for (int off = 32; off; off >>= 1) ss += __shfl_xor(ss, off);
    if (lane == 0) atomicAdd(sse, ss);
  }

  // flush avg_probs contributions: LDS accumulate, then one global atom/elem
  atomicAdd(&avg_s[co + 0], cav0.x);   atomicAdd(&avg_s[co + 1], cav0.y);
  atomicAdd(&avg_s[co + 2], cav0.z);   atomicAdd(&avg_s[co + 3], cav0.w);
  atomicAdd(&avg_s[co + 256], cav1.x); atomicAdd(&avg_s[co + 257], cav1.y);
  atomicAdd(&avg_s[co + 258], cav1.z); atomicAdd(&avg_s[co + 259], cav1.w);
  atomicAdd(&avg_s[co + 512], cav2.x); atomicAdd(&avg_s[co + 513], cav2.y);
  atomicAdd(&avg_s[co + 514], cav2.z); atomicAdd(&avg_s[co + 515], cav2.w);
  atomicAdd(&avg_s[co + 768], cav3.x); atomicAdd(&avg_s[co + 769], cav3.y);
  atomicAdd(&avg_s[co + 770], cav3.z); atomicAdd(&avg_s[co + 771], cav3.w);
  __syncthreads();
  atomicAdd(&avg_acc[t], avg_s[t]);
  atomicAdd(&avg_acc[t + 512], avg_s[t + 512]);
}

// ---------------------------------------------------------------------------
__global__ __launch_bounds__(1024)
void finalize(const float* __restrict__ avg_acc, const int* __restrict__ counts,
              const float* __restrict__ sse, float* __restrict__ out) {
  __shared__ float red[32];
  const int t = threadIdx.x;
  const float invN = 1.f / 32768.f;
  const float p = (float)counts[t] * invN;
  float a = p * log2f(p + 1e-10f);
  const float q = avg_acc[t] * invN;
  float b = q * log2f(q + 1e-10f);
#pragma unroll
  for (int off = 32; off; off >>= 1) {
    a += __shfl_xor(a, off);
    b += __shfl_xor(b, off);
  }
  const int wv = t >> 6, ln = t & 63;
  if (ln == 0) { red[wv] = a; red[wv + 16] = b; }
  __syncthreads();
  if (t == 0) {
    float sa = 0.f, sb = 0.f;
#pragma unroll
    for (int i = 0; i < 16; ++i) { sa += red[i]; sb += red[i + 16]; }
    out[QOFF + 0] = -sa;                               // code_perplexity
    out[QOFF + 1] = -sb;                               // prob_perplexity
    out[QOFF + 2] = sse[0] * (1.f / (32768.f * 512.f)); // commitment_loss
  }
}

// ---------------------------------------------------------------------------
extern "C" void kernel_launch(void* const* d_in, const int* in_sizes, int n_in,
                              void* d_out, int out_size, void* d_ws,
                              size_t ws_size, hipStream_t stream) {
  const float* x = (const float*)d_in[0];
  const float* e = (const float*)d_in[1];
  const float* g = (const float*)d_in[2];
  float* out = (float*)d_out;
  float* ws = (float*)d_ws;
  // ws layout (floats): [0,1024) esq | [1024,2048) avg_acc |
  //                     [2048,3072) counts(int) | [3072] sse | [4096, +512K) Et
  float* esq = ws;
  float* avg_acc = ws + 1024;
  int* counts = (int*)(ws + 2048);
  float* sse = ws + 3072;
  float* et = ws + 4096;  // 512*1024 floats = 2 MB  (needs ws_size >= ~2.02 MB)

  // zero the cross-block accumulators (ws is poisoned 0xAA, not re-zeroed)
  hipMemsetAsync(avg_acc, 0, (1024 + 1024 + 1) * sizeof(float), stream);

  transpose_e<<<128, 256, 0, stream>>>(e, et);
  esq_kernel<<<256, 256, 0, stream>>>(e, esq);
  vq_main<<<NTOT / BN, 512, 0, stream>>>(x, e, et, g, esq, out, avg_acc, counts,
                                         sse);
  finalize<<<1, 1024, 0, stream>>>(avg_acc, counts, sse, out);
}

// Round 2
// 505.335 us; speedup vs baseline: 1.5828x; 1.5828x over previous
//
#include <hip/hip_runtime.h>
#include <math.h>

// Problem constants (GumbelVectorQuantizer): B=16,T=2048,D=512,M=1024
#define NTOT 32768   // B*T
#define DDIM 512
#define MDIM 1024
#define BN   32      // rows per block
#define QOFF 16777216  // quantized element count (output scalars follow)

typedef _Float16 f16x8 __attribute__((ext_vector_type(8)));
typedef float    f32x4 __attribute__((ext_vector_type(4)));

// ---------------------------------------------------------------------------
// esq[m] = sum_d e[m][d]^2   (tree-reduced: accuracy matters for argmax)
__global__ __launch_bounds__(256) void esq_kernel(const float* __restrict__ e,
                                                  float* __restrict__ esq) {
  const int w = threadIdx.x >> 6, lane = threadIdx.x & 63;
  const int m = blockIdx.x * 4 + w;
  const float4* row = (const float4*)(e + (size_t)m * DDIM);
  const float4 a = row[lane * 2];
  const float4 b = row[lane * 2 + 1];
  float s = ((a.x * a.x + a.y * a.y) + (a.z * a.z + a.w * a.w)) +
            ((b.x * b.x + b.y * b.y) + (b.z * b.z + b.w * b.w));
#pragma unroll
  for (int off = 32; off; off >>= 1) s += __shfl_xor(s, off);
  if (lane == 0) esq[m] = s;
}

// ---------------------------------------------------------------------------
// Pre-swizzle E into MFMA B-fragment order, fp16 hi/lo split.
// Fragment id F = ctg*16 + ks  (ctg in [0,64): 16-col tile; ks in [0,16): K-step).
// Lane l, elem j holds B[k = ks*32 + (l>>4)*8 + j][col = ctg*16 + (l&15)]
//                    = E[m = ctg*16+(l&15)][k].
// Flat half index: (F*64 + lane)*8 + j  -> one thread writes 16B contiguous.
__global__ __launch_bounds__(256) void e_to_frag(const float* __restrict__ e,
                                                 _Float16* __restrict__ hi,
                                                 _Float16* __restrict__ lo) {
  const int tid = blockIdx.x * 256 + threadIdx.x;   // 65536 threads
  const int lane = tid & 63;
  const int F = tid >> 6;
  const int ctg = F >> 4, ks = F & 15;
  const int m = ctg * 16 + (lane & 15);
  const int k0 = ks * 32 + (lane >> 4) * 8;
  const float* src = e + (size_t)m * DDIM + k0;
  const float4 a = *(const float4*)src;
  const float4 b = *(const float4*)(src + 4);
  const float v0 = a.x, v1 = a.y, v2 = a.z, v3 = a.w;
  const float v4 = b.x, v5 = b.y, v6 = b.z, v7 = b.w;
  f16x8 vh, vl;
  vh[0] = (_Float16)v0; vl[0] = (_Float16)(v0 - (float)vh[0]);
  vh[1] = (_Float16)v1; vl[1] = (_Float16)(v1 - (float)vh[1]);
  vh[2] = (_Float16)v2; vl[2] = (_Float16)(v2 - (float)vh[2]);
  vh[3] = (_Float16)v3; vl[3] = (_Float16)(v3 - (float)vh[3]);
  vh[4] = (_Float16)v4; vl[4] = (_Float16)(v4 - (float)vh[4]);
  vh[5] = (_Float16)v5; vl[5] = (_Float16)(v5 - (float)vh[5]);
  vh[6] = (_Float16)v6; vl[6] = (_Float16)(v6 - (float)vh[6]);
  vh[7] = (_Float16)v7; vl[7] = (_Float16)(v7 - (float)vh[7]);
  *(f16x8*)(hi + (size_t)tid * 8) = vh;
  *(f16x8*)(lo + (size_t)tid * 8) = vl;
}

// ---------------------------------------------------------------------------
#define AMAX(V, MM)                                                            \
  { const float v_ = (V); const int m_ = (MM);                                 \
    if (v_ > bv || (v_ == bv && m_ < bi)) { bv = v_; bi = m_; } }
#define GMAX(V, MM)                                                            \
  { const float v_ = (V); const int m_ = (MM);                                 \
    if (v_ > gv || (v_ == gv && m_ < gi)) { gv = v_; gi = m_; } }

// Main fused kernel: G = X.E^T via fp16x2-split MFMA (3 mfma per K-tile),
// then per-row argmax / softmax->avg_probs / gumbel argmax -> gather + SSE.
// 8 waves/block; wave owns 32 rows x 128 cols = 2x8 tiles of 16x16.
__global__ __launch_bounds__(512)
void vq_main(const float* __restrict__ x, const float* __restrict__ emb,
             const _Float16* __restrict__ ehi, const _Float16* __restrict__ elo,
             const float* __restrict__ gum, const float* __restrict__ esq,
             float* __restrict__ out, float* __restrict__ avg_acc,
             int* __restrict__ counts, float* __restrict__ sse) {
  __shared__ float Lds[16 * 1028];   // one 16-row G slab, padded (+4) stride
  __shared__ float esq_s[MDIM];
  __shared__ float avg_s[MDIM];

  const int t = threadIdx.x;
  const int w = t >> 6;
  const int lane = t & 63;
  const int l15 = lane & 15;
  const int lg = lane >> 4;
  const int co = lane << 2;
  const int n0 = blockIdx.x * BN;

  avg_s[t] = 0.f; avg_s[t + 512] = 0.f;
  esq_s[t] = esq[t]; esq_s[t + 512] = esq[t + 512];

  f32x4 acc[2][8];
#pragma unroll
  for (int rt = 0; rt < 2; ++rt)
#pragma unroll
    for (int ct = 0; ct < 8; ++ct) acc[rt][ct] = (f32x4){0.f, 0.f, 0.f, 0.f};

  const float* xb = x + (size_t)n0 * DDIM;

  for (int ks = 0; ks < 16; ++ks) {
    const int k0 = ks * 32 + lg * 8;
    // A fragments: rows n0 + rt*16 + (l&15), k = k0..k0+8; fp32 -> hi/lo fp16
    f16x8 Ah[2], Al[2];
#pragma unroll
    for (int rt = 0; rt < 2; ++rt) {
      const float* xr = xb + (size_t)(rt * 16 + l15) * DDIM + k0;
      const float4 a = *(const float4*)xr;
      const float4 b = *(const float4*)(xr + 4);
      const float v0 = a.x, v1 = a.y, v2 = a.z, v3 = a.w;
      const float v4 = b.x, v5 = b.y, v6 = b.z, v7 = b.w;
      Ah[rt][0] = (_Float16)v0; Al[rt][0] = (_Float16)(v0 - (float)Ah[rt][0]);
      Ah[rt][1] = (_Float16)v1; Al[rt][1] = (_Float16)(v1 - (float)Ah[rt][1]);
      Ah[rt][2] = (_Float16)v2; Al[rt][2] = (_Float16)(v2 - (float)Ah[rt][2]);
      Ah[rt][3] = (_Float16)v3; Al[rt][3] = (_Float16)(v3 - (float)Ah[rt][3]);
      Ah[rt][4] = (_Float16)v4; Al[rt][4] = (_Float16)(v4 - (float)Ah[rt][4]);
      Ah[rt][5] = (_Float16)v5; Al[rt][5] = (_Float16)(v5 - (float)Ah[rt][5]);
      Ah[rt][6] = (_Float16)v6; Al[rt][6] = (_Float16)(v6 - (float)Ah[rt][6]);
      Ah[rt][7] = (_Float16)v7; Al[rt][7] = (_Float16)(v7 - (float)Ah[rt][7]);
    }
#pragma unroll
    for (int ct = 0; ct < 8; ++ct) {
      const size_t foff = (((size_t)(w * 8 + ct) * 16 + ks) * 64 + lane) * 8;
      const f16x8 Bh = *(const f16x8*)(ehi + foff);
      const f16x8 Bl = *(const f16x8*)(elo + foff);
#pragma unroll
      for (int rt = 0; rt < 2; ++rt) {
        acc[rt][ct] = __builtin_amdgcn_mfma_f32_16x16x32_f16(Ah[rt], Bh, acc[rt][ct], 0, 0, 0);
        acc[rt][ct] = __builtin_amdgcn_mfma_f32_16x16x32_f16(Al[rt], Bh, acc[rt][ct], 0, 0, 0);
        acc[rt][ct] = __builtin_amdgcn_mfma_f32_16x16x32_f16(Ah[rt], Bl, acc[rt][ct], 0, 0, 0);
      }
    }
  }

  // ----- epilogue: two passes of 16 rows through LDS, round-1 row logic -----
  __syncthreads();  // esq_s/avg_s ready
  const float4 es0 = *(const float4*)&esq_s[co];
  const float4 es1 = *(const float4*)&esq_s[co + 256];
  const float4 es2 = *(const float4*)&esq_s[co + 512];
  const float4 es3 = *(const float4*)&esq_s[co + 768];
  float4 cav0 = make_float4(0.f, 0.f, 0.f, 0.f);
  float4 cav1 = make_float4(0.f, 0.f, 0.f, 0.f);
  float4 cav2 = make_float4(0.f, 0.f, 0.f, 0.f);
  float4 cav3 = make_float4(0.f, 0.f, 0.f, 0.f);

#pragma unroll
  for (int pass = 0; pass < 2; ++pass) {
    // scatter this pass's row-tile to LDS: C/D layout row=(lg*4+reg), col per ct
#pragma unroll
    for (int ct = 0; ct < 8; ++ct) {
      const int col = w * 128 + ct * 16 + l15;
#pragma unroll
      for (int rg = 0; rg < 4; ++rg)
        Lds[(lg * 4 + rg) * 1028 + col] = acc[pass][ct][rg];
    }
    __syncthreads();

#pragma unroll
    for (int i = 0; i < 2; ++i) {
      const int lr = 2 * w + i;
      const int n = n0 + pass * 16 + lr;
      const float* Lr = &Lds[lr * 1028];
      const float4 g0 = *(const float4*)&Lr[co];
      const float4 g1 = *(const float4*)&Lr[co + 256];
      const float4 g2 = *(const float4*)&Lr[co + 512];
      const float4 g3 = *(const float4*)&Lr[co + 768];
      // dmap' (row-shift-invariant part): 10*G - 5*||e||^2
      float4 d0, d1, d2, d3;
      d0.x = 10.f * g0.x - 5.f * es0.x; d0.y = 10.f * g0.y - 5.f * es0.y;
      d0.z = 10.f * g0.z - 5.f * es0.z; d0.w = 10.f * g0.w - 5.f * es0.w;
      d1.x = 10.f * g1.x - 5.f * es1.x; d1.y = 10.f * g1.y - 5.f * es1.y;
      d1.z = 10.f * g1.z - 5.f * es1.z; d1.w = 10.f * g1.w - 5.f * es1.w;
      d2.x = 10.f * g2.x - 5.f * es2.x; d2.y = 10.f * g2.y - 5.f * es2.y;
      d2.z = 10.f * g2.z - 5.f * es2.z; d2.w = 10.f * g2.w - 5.f * es2.w;
      d3.x = 10.f * g3.x - 5.f * es3.x; d3.y = 10.f * g3.y - 5.f * es3.y;
      d3.z = 10.f * g3.z - 5.f * es3.z; d3.w = 10.f * g3.w - 5.f * es3.w;

      // hard argmax (first-index tiebreak)
      float bv = -3.402823466e+38f; int bi = 0;
      AMAX(d0.x, co + 0)   AMAX(d0.y, co + 1)   AMAX(d0.z, co + 2)   AMAX(d0.w, co + 3)
      AMAX(d1.x, co + 256) AMAX(d1.y, co + 257) AMAX(d1.z, co + 258) AMAX(d1.w, co + 259)
      AMAX(d2.x, co + 512) AMAX(d2.y, co + 513) AMAX(d2.z, co + 514) AMAX(d2.w, co + 515)
      AMAX(d3.x, co + 768) AMAX(d3.y, co + 769) AMAX(d3.z, co + 770) AMAX(d3.w, co + 771)
#pragma unroll
      for (int off = 32; off; off >>= 1) {
        const float ov = __shfl_xor(bv, off);
        const int oi = __shfl_xor(bi, off);
        if (ov > bv || (ov == bv && oi < bi)) { bv = ov; bi = oi; }
      }
      if (lane == 0) atomicAdd(&counts[bi], 1);

      // softmax(dmap) -> avg_probs contribution (bv is the row max)
      float4 p0, p1, p2, p3;
      p0.x = __expf(d0.x - bv); p0.y = __expf(d0.y - bv); p0.z = __expf(d0.z - bv); p0.w = __expf(d0.w - bv);
      p1.x = __expf(d1.x - bv); p1.y = __expf(d1.y - bv); p1.z = __expf(d1.z - bv); p1.w = __expf(d1.w - bv);
      p2.x = __expf(d2.x - bv); p2.y = __expf(d2.y - bv); p2.z = __expf(d2.z - bv); p2.w = __expf(d2.w - bv);
      p3.x = __expf(d3.x - bv); p3.y = __expf(d3.y - bv); p3.z = __expf(d3.z - bv); p3.w = __expf(d3.w - bv);
      float ssum = (((p0.x + p0.y) + (p0.z + p0.w)) + ((p1.x + p1.y) + (p1.z + p1.w))) +
                   (((p2.x + p2.y) + (p2.z + p2.w)) + ((p3.x + p3.y) + (p3.z + p3.w)));
#pragma unroll
      for (int off = 32; off; off >>= 1) ssum += __shfl_xor(ssum, off);
      const float inv = 1.0f / ssum;
      cav0.x += p0.x * inv; cav0.y += p0.y * inv; cav0.z += p0.z * inv; cav0.w += p0.w * inv;
      cav1.x += p1.x * inv; cav1.y += p1.y * inv; cav1.z += p1.z * inv; cav1.w += p1.w * inv;
      cav2.x += p2.x * inv; cav2.y += p2.y * inv; cav2.z += p2.z * inv; cav2.w += p2.w * inv;
      cav3.x += p3.x * inv; cav3.y += p3.y * inv; cav3.z += p3.z * inv; cav3.w += p3.w * inv;

      // gumbel path argmax -> quantized index
      const float4* grow = (const float4*)(gum + (size_t)n * MDIM);
      float gv = -3.402823466e+38f; int gi = 0;
      {
        const float4 q0 = grow[lane];
        const float4 q1 = grow[lane + 64];
        const float4 q2 = grow[lane + 128];
        const float4 q3 = grow[lane + 192];
        GMAX(d0.x + q0.x, co + 0)   GMAX(d0.y + q0.y, co + 1)
        GMAX(d0.z + q0.z, co + 2)   GMAX(d0.w + q0.w, co + 3)
        GMAX(d1.x + q1.x, co + 256) GMAX(d1.y + q1.y, co + 257)
        GMAX(d1.z + q1.z, co + 258) GMAX(d1.w + q1.w, co + 259)
        GMAX(d2.x + q2.x, co + 512) GMAX(d2.y + q2.y, co + 513)
        GMAX(d2.z + q2.z, co + 514) GMAX(d2.w + q2.w, co + 515)
        GMAX(d3.x + q3.x, co + 768) GMAX(d3.y + q3.y, co + 769)
        GMAX(d3.z + q3.z, co + 770) GMAX(d3.w + q3.w, co + 771)
      }
#pragma unroll
      for (int off = 32; off; off >>= 1) {
        const float ov = __shfl_xor(gv, off);
        const int oi = __shfl_xor(gi, off);
        if (ov > gv || (ov == gv && oi < gi)) { gv = ov; gi = oi; }
      }

      // quantized[n] = embedding[gi]; commitment SSE
      const float4* erow = (const float4*)(emb + (size_t)gi * DDIM);
      const float4* xrow = (const float4*)(x + (size_t)n * DDIM);
      float4* orow = (float4*)(out + (size_t)n * DDIM);
      float ss = 0.f;
#pragma unroll
      for (int c2 = 0; c2 < 2; ++c2) {
        const int f = lane + 64 * c2;
        const float4 ev = erow[f];
        const float4 xv = xrow[f];
        orow[f] = ev;
        const float q0 = xv.x - ev.x, q1 = xv.y - ev.y;
        const float q2 = xv.z - ev.z, q3 = xv.w - ev.w;
        ss += (q0 * q0 + q1 * q1) + (q2 * q2 + q3 * q3);
      }
#pragma unroll
      for (int off = 32; off; off >>= 1) ss += __shfl_xor(ss, off);
      if (lane == 0) atomicAdd(sse, ss);
    }
    __syncthreads();  // Lds reused by next pass
  }

  // flush avg_probs contributions: LDS accumulate, then one global atom/elem
  atomicAdd(&avg_s[co + 0], cav0.x);   atomicAdd(&avg_s[co + 1], cav0.y);
  atomicAdd(&avg_s[co + 2], cav0.z);   atomicAdd(&avg_s[co + 3], cav0.w);
  atomicAdd(&avg_s[co + 256], cav1.x); atomicAdd(&avg_s[co + 257], cav1.y);
  atomicAdd(&avg_s[co + 258], cav1.z); atomicAdd(&avg_s[co + 259], cav1.w);
  atomicAdd(&avg_s[co + 512], cav2.x); atomicAdd(&avg_s[co + 513], cav2.y);
  atomicAdd(&avg_s[co + 514], cav2.z); atomicAdd(&avg_s[co + 515], cav2.w);
  atomicAdd(&avg_s[co + 768], cav3.x); atomicAdd(&avg_s[co + 769], cav3.y);
  atomicAdd(&avg_s[co + 770], cav3.z); atomicAdd(&avg_s[co + 771], cav3.w);
  __syncthreads();
  atomicAdd(&avg_acc[t], avg_s[t]);
  atomicAdd(&avg_acc[t + 512], avg_s[t + 512]);
}

// ---------------------------------------------------------------------------
__global__ __launch_bounds__(1024)
void finalize(const float* __restrict__ avg_acc, const int* __restrict__ counts,
              const float* __restrict__ sse, float* __restrict__ out) {
  __shared__ float red[32];
  const int t = threadIdx.x;
  const float invN = 1.f / 32768.f;
  const float p = (float)counts[t] * invN;
  float a = p * log2f(p + 1e-10f);
  const float q = avg_acc[t] * invN;
  float b = q * log2f(q + 1e-10f);
#pragma unroll
  for (int off = 32; off; off >>= 1) {
    a += __shfl_xor(a, off);
    b += __shfl_xor(b, off);
  }
  const int wv = t >> 6, ln = t & 63;
  if (ln == 0) { red[wv] = a; red[wv + 16] = b; }
  __syncthreads();
  if (t == 0) {
    float sa = 0.f, sb = 0.f;
#pragma unroll
    for (int i = 0; i < 16; ++i) { sa += red[i]; sb += red[i + 16]; }
    out[QOFF + 0] = -sa;                                // code_perplexity
    out[QOFF + 1] = -sb;                                // prob_perplexity
    out[QOFF + 2] = sse[0] * (1.f / (32768.f * 512.f)); // commitment_loss
  }
}

// ---------------------------------------------------------------------------
extern "C" void kernel_launch(void* const* d_in, const int* in_sizes, int n_in,
                              void* d_out, int out_size, void* d_ws,
                              size_t ws_size, hipStream_t stream) {
  const float* x = (const float*)d_in[0];
  const float* e = (const float*)d_in[1];
  const float* g = (const float*)d_in[2];
  float* out = (float*)d_out;
  float* ws = (float*)d_ws;
  // ws layout (floats): [0,1024) esq | [1024,2048) avg_acc |
  //   [2048,3072) counts(int) | [3072] sse | [4096, +512K) Ehi/Elo fragments
  float* esq = ws;
  float* avg_acc = ws + 1024;
  int* counts = (int*)(ws + 2048);
  float* sse = ws + 3072;
  _Float16* ehi = (_Float16*)(ws + 4096);        // 1024*512 halves = 1 MB
  _Float16* elo = ehi + (size_t)MDIM * DDIM;     // 1 MB

  // zero the cross-block accumulators (ws is poisoned 0xAA, not re-zeroed)
  hipMemsetAsync(avg_acc, 0, (1024 + 1024 + 1) * sizeof(float), stream);

  e_to_frag<<<256, 256, 0, stream>>>(e, ehi, elo);
  esq_kernel<<<256, 256, 0, stream>>>(e, esq);
  vq_main<<<NTOT / BN, 512, 0, stream>>>(x, e, ehi, elo, g, esq, out, avg_acc,
                                         counts, sse);
  finalize<<<1, 1024, 0, stream>>>(avg_acc, counts, sse, out);
}